// Round 1
// baseline (1772.264 us; speedup 1.0000x reference)
//
#include <hip/hip_runtime.h>
#include <cstddef>

#define D 1024
#define H 16
#define KS 64
#define S 2048
#define B 2
#define M_ROWS (B * S)      // 4096
#define NT (S / 64)         // 32 key tiles per row for softmax partials
#define NEG_BIG_F (-1.0e9f)

#define BM 128
#define BN 64
#define BK 32
// 256 threads: tx = tid&15 -> 4 output cols each (64), ty = tid>>4 -> 8 rows each (128)

// Inner product over one staged K-slab. As is k-major [BK][132] (pad->writes 4-way max,
// frag reads broadcast + conflict-free). Bs k-major, frag read 2-way (free).
// 32 FMA per 3 x ds_read_b128 per kk step.
#define GEMM_INNER(AS, BS)                                              \
    _Pragma("unroll")                                                   \
    for (int kk = 0; kk < BK; kk++) {                                   \
        float4 a0 = *(const float4*)&AS[kk][ty * 8];                    \
        float4 a1 = *(const float4*)&AS[kk][ty * 8 + 4];                \
        float4 b4 = *(const float4*)&BS[kk][tx * 4];                    \
        float av[8] = {a0.x, a0.y, a0.z, a0.w, a1.x, a1.y, a1.z, a1.w}; \
        float bv[4] = {b4.x, b4.y, b4.z, b4.w};                         \
        _Pragma("unroll")                                               \
        for (int i = 0; i < 8; i++)                                     \
            _Pragma("unroll")                                           \
            for (int j = 0; j < 4; j++) acc[i][j] += av[i] * bv[j];     \
    }

// ---------------------------------------------------------------------------
// C[M_ROWS, D] = A[M_ROWS, D] @ W[D, D] + bias.  permute==1: write [B,H,S,64].
// grid (D/BN=16, M_ROWS/BM=32), 256 threads.
// ---------------------------------------------------------------------------
__global__ __launch_bounds__(256) void gemm_proj(
    const float* __restrict__ A, const float* __restrict__ W,
    const float* __restrict__ bias, float* __restrict__ C, int permute)
{
    __shared__ __align__(16) float As[BK][132];
    __shared__ __align__(16) float Bs[BK][64];

    const int tile_m = blockIdx.y * BM;
    const int tile_n = blockIdx.x * BN;
    const int tid = threadIdx.x;
    const int tx = tid & 15;
    const int ty = tid >> 4;

    float acc[8][4] = {};

    for (int k0 = 0; k0 < D; k0 += BK) {
        // A tile 128x32, transposed into As[k][m]
#pragma unroll
        for (int p = 0; p < 4; p++) {
            int idx = tid + p * 256;
            int m = idx >> 3, c = idx & 7;
            float4 v = *(const float4*)&A[(size_t)(tile_m + m) * D + k0 + c * 4];
            As[c * 4 + 0][m] = v.x; As[c * 4 + 1][m] = v.y;
            As[c * 4 + 2][m] = v.z; As[c * 4 + 3][m] = v.w;
        }
        // B tile 32x64, direct copy (row-major in k)
#pragma unroll
        for (int p = 0; p < 2; p++) {
            int idx = tid + p * 256;
            int r = idx >> 4, c4 = idx & 15;
            *(float4*)&Bs[r][c4 * 4] =
                *(const float4*)&W[(size_t)(k0 + r) * D + tile_n + c4 * 4];
        }
        __syncthreads();
        GEMM_INNER(As, Bs)
        __syncthreads();
    }

    const float4 b4 = *(const float4*)&bias[tile_n + tx * 4];
#pragma unroll
    for (int i = 0; i < 8; i++) {
        int row = tile_m + ty * 8 + i;
        int n0 = tile_n + tx * 4;
        float4 o;
        o.x = acc[i][0] + b4.x; o.y = acc[i][1] + b4.y;
        o.z = acc[i][2] + b4.z; o.w = acc[i][3] + b4.w;
        if (permute) {
            int bb = row >> 11, ss = row & (S - 1);
            int hh = tile_n >> 6, dd = tx * 4;   // BN==64: one head per tile
            *(float4*)&C[(((size_t)(bb * H + hh) * S + ss) << 6) + dd] = o;
        } else {
            *(float4*)&C[(size_t)row * D + n0] = o;
        }
    }
}

// ---------------------------------------------------------------------------
// scores: Sc[m][n] = 0.125 * Q[m]·K[n], mask semantics, write raw masked score.
// Also emits per-(row, 64-col tile) softmax partials (tile max, tile sumexp).
// grid (S/BN=32, S/BM=16, B*H).
// ---------------------------------------------------------------------------
__global__ __launch_bounds__(256) void scores_kernel(
    const float* __restrict__ Q, const float* __restrict__ K,
    const float* __restrict__ mask, float* __restrict__ Sc,
    float2* __restrict__ aux)
{
    const int bh = blockIdx.z;
    const int tile_m = blockIdx.y * BM;
    const int tile_n = blockIdx.x * BN;
    const int b = bh >> 4;
    const int tid = threadIdx.x;
    const int tx = tid & 15;
    const int ty = tid >> 4;

    __shared__ __align__(16) float As[BK][132];
    __shared__ __align__(16) float Bs[BK][68];   // transposed writes: pad 68

    const float* Qh = Q + (((size_t)bh * S) << 6);
    const float* Kh = K + (((size_t)bh * S) << 6);

    float acc[8][4] = {};

    for (int k0 = 0; k0 < KS; k0 += BK) {   // 2 iterations
#pragma unroll
        for (int p = 0; p < 4; p++) {
            int idx = tid + p * 256;
            int m = idx >> 3, c = idx & 7;
            float4 v = *(const float4*)&Qh[((size_t)(tile_m + m) << 6) + k0 + c * 4];
            As[c * 4 + 0][m] = v.x; As[c * 4 + 1][m] = v.y;
            As[c * 4 + 2][m] = v.z; As[c * 4 + 3][m] = v.w;
        }
        // K^T tile: Bs[k][n] = K[tile_n+n][k0+k]
#pragma unroll
        for (int p = 0; p < 2; p++) {
            int idx = tid + p * 256;
            int n = idx >> 3, c = idx & 7;
            float4 v = *(const float4*)&Kh[((size_t)(tile_n + n) << 6) + k0 + c * 4];
            Bs[c * 4 + 0][n] = v.x; Bs[c * 4 + 1][n] = v.y;
            Bs[c * 4 + 2][n] = v.z; Bs[c * 4 + 3][n] = v.w;
        }
        __syncthreads();
        GEMM_INNER(As, Bs)
        __syncthreads();
    }

    const float* mb = mask + (size_t)b * S * S;
    float* Sh = Sc + (size_t)bh * S * S;
#pragma unroll
    for (int i = 0; i < 8; i++) {
        const int m = tile_m + ty * 8 + i;
        const int n0 = tile_n + tx * 4;
        const float4 mk = *(const float4*)&mb[(size_t)m * S + n0];
        float s0 = acc[i][0] * 0.125f * mk.x; if (s0 == 0.0f) s0 = NEG_BIG_F;
        float s1 = acc[i][1] * 0.125f * mk.y; if (s1 == 0.0f) s1 = NEG_BIG_F;
        float s2 = acc[i][2] * 0.125f * mk.z; if (s2 == 0.0f) s2 = NEG_BIG_F;
        float s3 = acc[i][3] * 0.125f * mk.w; if (s3 == 0.0f) s3 = NEG_BIG_F;
        float4 o = {s0, s1, s2, s3};
        *(float4*)&Sh[(size_t)m * S + n0] = o;

        // row-tile softmax partials across the 16 tx lanes (contiguous in wave)
        float mx = fmaxf(fmaxf(s0, s1), fmaxf(s2, s3));
#pragma unroll
        for (int d = 1; d < 16; d <<= 1) mx = fmaxf(mx, __shfl_xor(mx, d));
        float ls = __expf(s0 - mx) + __expf(s1 - mx) +
                   __expf(s2 - mx) + __expf(s3 - mx);
#pragma unroll
        for (int d = 1; d < 16; d <<= 1) ls += __shfl_xor(ls, d);
        if (tx == 0)
            aux[((size_t)bh * S + m) * NT + blockIdx.x] = make_float2(mx, ls);
    }
}

// ---------------------------------------------------------------------------
// combine per-tile partials -> per-row (max, 1/sum). One thread per row.
// ---------------------------------------------------------------------------
__global__ __launch_bounds__(256) void reduce_stats(
    const float2* __restrict__ aux, float2* __restrict__ stats)
{
    const int row = blockIdx.x * 256 + threadIdx.x;   // < B*H*S
    const float2* a = aux + (size_t)row * NT;
    float m = -3.0e38f;
#pragma unroll
    for (int t = 0; t < NT; t++) m = fmaxf(m, a[t].x);
    float l = 0.0f;
#pragma unroll
    for (int t = 0; t < NT; t++) l += a[t].y * __expf(a[t].x - m);
    stats[row] = make_float2(m, 1.0f / l);
}

// ---------------------------------------------------------------------------
// pv: reads raw scores, normalizes on the fly (p = exp(s-m)*inv_l), writes the
// normalized alignment back in place, accumulates Ctx = P @ V.
// grid (1, S/BM=16, B*H).
// ---------------------------------------------------------------------------
__global__ __launch_bounds__(256) void pv_kernel(
    float* __restrict__ P, const float* __restrict__ V,
    const float2* __restrict__ stats, float* __restrict__ Ctx)
{
    const int bh = blockIdx.z;
    const int tile_m = blockIdx.y * BM;
    const int b = bh >> 4;
    const int h = bh & 15;
    const int tid = threadIdx.x;
    const int tx = tid & 15;
    const int ty = tid >> 4;

    __shared__ __align__(16) float As[BK][132];
    __shared__ __align__(16) float Bs[BK][64];
    __shared__ float2 st[BM];

    float* Ph = P + (size_t)bh * S * S;
    const float* Vh = V + (((size_t)bh * S) << 6);

    if (tid < BM) st[tid] = stats[(size_t)bh * S + tile_m + tid];
    __syncthreads();

    float acc[8][4] = {};

    for (int k0 = 0; k0 < S; k0 += BK) {
        // P tile 128x32: load raw, normalize, write back, transpose into LDS
#pragma unroll
        for (int p = 0; p < 4; p++) {
            int idx = tid + p * 256;
            int m = idx >> 3, c = idx & 7;
            float* gp = &Ph[(size_t)(tile_m + m) * S + k0 + c * 4];
            float4 v = *(const float4*)gp;
            float2 s2 = st[m];
            v.x = __expf(v.x - s2.x) * s2.y;
            v.y = __expf(v.y - s2.x) * s2.y;
            v.z = __expf(v.z - s2.x) * s2.y;
            v.w = __expf(v.w - s2.x) * s2.y;
            *(float4*)gp = v;
            As[c * 4 + 0][m] = v.x; As[c * 4 + 1][m] = v.y;
            As[c * 4 + 2][m] = v.z; As[c * 4 + 3][m] = v.w;
        }
        // V tile 32x64 direct
#pragma unroll
        for (int p = 0; p < 2; p++) {
            int idx = tid + p * 256;
            int r = idx >> 4, c4 = idx & 15;
            *(float4*)&Bs[r][c4 * 4] =
                *(const float4*)&Vh[((size_t)(k0 + r) << 6) + c4 * 4];
        }
        __syncthreads();
        GEMM_INNER(As, Bs)
        __syncthreads();
    }

#pragma unroll
    for (int i = 0; i < 8; i++) {
        int m = tile_m + ty * 8 + i;
        float4 o = {acc[i][0], acc[i][1], acc[i][2], acc[i][3]};
        *(float4*)&Ctx[(size_t)(b * S + m) * D + h * 64 + tx * 4] = o;
    }
}

// ---------------------------------------------------------------------------
extern "C" void kernel_launch(void* const* d_in, const int* in_sizes, int n_in,
                              void* d_out, int out_size, void* d_ws, size_t ws_size,
                              hipStream_t stream)
{
    const float* q    = (const float*)d_in[0];
    const float* v    = (const float*)d_in[1];
    const float* mask = (const float*)d_in[2];
    const float* wq_w = (const float*)d_in[3];
    const float* wq_b = (const float*)d_in[4];
    const float* wk_w = (const float*)d_in[5];
    const float* wk_b = (const float*)d_in[6];
    const float* wv_w = (const float*)d_in[7];
    const float* wv_b = (const float*)d_in[8];
    const float* wo_w = (const float*)d_in[9];
    const float* wo_b = (const float*)d_in[10];

    float* out_heads = (float*)d_out;                       // [B,S,D]
    float* out_align = (float*)d_out + (size_t)B * S * D;   // [B,H,S,S]

    const size_t qkv = (size_t)B * H * S * KS;              // 4,194,304 floats
    float*  Qw    = (float*)d_ws;
    float*  Kw    = Qw + qkv;
    float*  Vw    = Kw + qkv;
    float*  Ctx   = Vw + qkv;                               // [B*S, D]
    // aux (softmax partials, 16.8 MB) aliases Ctx: aux is dead before pv
    // writes Ctx, so no lifetime overlap.
    float2* aux   = (float2*)Ctx;                           // [B*H*S][NT]
    float2* stats = (float2*)(Ctx + qkv);                   // [B*H*S]

    dim3 pgrid(D / BN, M_ROWS / BM);        // (16, 32)
    gemm_proj<<<pgrid, 256, 0, stream>>>(q, wq_w, wq_b, Qw, 1);
    gemm_proj<<<pgrid, 256, 0, stream>>>(v, wk_w, wk_b, Kw, 1);
    gemm_proj<<<pgrid, 256, 0, stream>>>(v, wv_w, wv_b, Vw, 1);

    dim3 sgrid(S / BN, S / BM, B * H);      // (32, 16, 32)
    scores_kernel<<<sgrid, 256, 0, stream>>>(Qw, Kw, mask, out_align, aux);

    reduce_stats<<<dim3((B * H * S) / 256), 256, 0, stream>>>(aux, stats);

    dim3 vgrid(1, S / BM, B * H);           // (1, 16, 32)
    pv_kernel<<<vgrid, 256, 0, stream>>>(out_align, Vw, stats, Ctx);

    gemm_proj<<<pgrid, 256, 0, stream>>>(Ctx, wo_w, wo_b, out_heads, 0);
}

// Round 2
// 1242.058 us; speedup vs baseline: 1.4269x; 1.4269x over previous
//
#include <hip/hip_runtime.h>
#include <cstddef>

#define D 1024
#define H 16
#define S 2048
#define B 2
#define M_ROWS (B * S)   // 4096
#define NT 16            // 128-col score tiles per row
#define NEG_BIG_F (-1.0e9f)

// bf16x3 fp32-emulation on MFMA:  x = hi + lo (bf16 RN each);
// a*b ~= ah*bh + ah*bl + al*bh  (drop al*bl ~ 2^-18 |ab|), fp32 accumulate.
typedef short bfrag __attribute__((ext_vector_type(8)));   // 8 bf16 = 4 VGPR
typedef float f32x4 __attribute__((ext_vector_type(4)));

__device__ __forceinline__ unsigned short bf_rn(float x) {
    unsigned u = __float_as_uint(x);
    u += 0x7FFFu + ((u >> 16) & 1u);      // round-to-nearest-even
    return (unsigned short)(u >> 16);
}
__device__ __forceinline__ float bf2f(unsigned short h) {
    return __uint_as_float(((unsigned)h) << 16);
}

__device__ __forceinline__ void load16(const float4* __restrict__ g, float (&x)[16]) {
#pragma unroll
    for (int q = 0; q < 4; q++) {
        float4 t = g[q];
        x[q*4+0] = t.x; x[q*4+1] = t.y; x[q*4+2] = t.z; x[q*4+3] = t.w;
    }
}

__device__ __forceinline__ void split16_store(const float (&x)[16],
                                              short* __restrict__ hp,
                                              short* __restrict__ lp) {
    __align__(16) short hs[16], ls[16];
#pragma unroll
    for (int e = 0; e < 16; e++) {
        unsigned short hh = bf_rn(x[e]);
        hs[e] = (short)hh;
        ls[e] = (short)bf_rn(x[e] - bf2f(hh));
    }
    *(bfrag*)(hp)     = *(const bfrag*)&hs[0];
    *(bfrag*)(hp + 8) = *(const bfrag*)&hs[8];
    *(bfrag*)(lp)     = *(const bfrag*)&ls[0];
    *(bfrag*)(lp + 8) = *(const bfrag*)&ls[8];
}

#define MFMA3(accv, AH, AL, BH, BL)                                          \
    accv = __builtin_amdgcn_mfma_f32_16x16x32_bf16(AH, BH, accv, 0, 0, 0);   \
    accv = __builtin_amdgcn_mfma_f32_16x16x32_bf16(AH, BL, accv, 0, 0, 0);   \
    accv = __builtin_amdgcn_mfma_f32_16x16x32_bf16(AL, BH, accv, 0, 0, 0);

// ---------------------------------------------------------------------------
// W [K][N] fp32 -> WT [N][K] fp32 (so both GEMM operands are k-contiguous)
// ---------------------------------------------------------------------------
__global__ __launch_bounds__(256) void transpose_w(
    const float* __restrict__ Win, float* __restrict__ WT)
{
    __shared__ float t[64][65];
    const int tid = threadIdx.x;
    const int bx = blockIdx.x * 64, by = blockIdx.y * 64;
    const int c = tid & 63, r0 = tid >> 6;
#pragma unroll
    for (int r = r0; r < 64; r += 4)
        t[r][c] = Win[(size_t)(by + r) * D + bx + c];
    __syncthreads();
#pragma unroll
    for (int r = r0; r < 64; r += 4)
        WT[(size_t)(bx + r) * D + by + c] = t[c][r];
}

// ---------------------------------------------------------------------------
// C[4096,1024] = A @ W + bias  via bf16x3 MFMA.  A fp32 [4096][1024],
// WT fp32 [N][K].  mode 0: row-major fp32 out.  mode 1: [B,H,S,64] out.
// mode 2: V^T out [B,H,64,S].
// Tile 128x64, BK=64, 4 waves (2x2), wave = 64x32 (4x2 frags).
// ---------------------------------------------------------------------------
#define PADK 72   // 64 + 8 shorts: 144B rows, conflict-free b128 frag reads

__global__ __launch_bounds__(256) void mm_proj(
    const float* __restrict__ A, const float* __restrict__ WT,
    const float* __restrict__ bias, float* __restrict__ Cout, int mode)
{
    __shared__ __align__(16) short Ah[128][PADK], Al[128][PADK];
    __shared__ __align__(16) short Bh[64][PADK],  Bl[64][PADK];

    const int tid  = threadIdx.x;
    const int lane = tid & 63, wid = tid >> 6;
    const int wm = (wid >> 1) * 64, wn = (wid & 1) * 32;
    const int lr = lane >> 4, lc = lane & 15;
    const int tile_n = blockIdx.x * 64;
    const int tile_m = blockIdx.y * 128;

    f32x4 acc[4][2] = {};

    for (int k0 = 0; k0 < D; k0 += 64) {
        __syncthreads();
        // A tile 128x64: 512 16-float segs, 2/thread
#pragma unroll
        for (int p = 0; p < 2; p++) {
            int s = tid + p * 256;
            int row = s >> 2, kseg = (s & 3) * 16;
            float x[16];
            load16((const float4*)&A[(size_t)(tile_m + row) * D + k0 + kseg], x);
            split16_store(x, &Ah[row][kseg], &Al[row][kseg]);
        }
        // B tile 64x64: 256 segs, 1/thread
        {
            int row = tid >> 2, kseg = (tid & 3) * 16;
            float x[16];
            load16((const float4*)&WT[(size_t)(tile_n + row) * D + k0 + kseg], x);
            split16_store(x, &Bh[row][kseg], &Bl[row][kseg]);
        }
        __syncthreads();
#pragma unroll
        for (int ks = 0; ks < 2; ks++) {
            const int ko = ks * 32 + lr * 8;
            bfrag ah[4], al[4], bh[2], bl[2];
#pragma unroll
            for (int fm = 0; fm < 4; fm++) {
                ah[fm] = *(const bfrag*)&Ah[wm + fm * 16 + lc][ko];
                al[fm] = *(const bfrag*)&Al[wm + fm * 16 + lc][ko];
            }
#pragma unroll
            for (int fn = 0; fn < 2; fn++) {
                bh[fn] = *(const bfrag*)&Bh[wn + fn * 16 + lc][ko];
                bl[fn] = *(const bfrag*)&Bl[wn + fn * 16 + lc][ko];
            }
#pragma unroll
            for (int fm = 0; fm < 4; fm++)
#pragma unroll
                for (int fn = 0; fn < 2; fn++) {
                    MFMA3(acc[fm][fn], ah[fm], al[fm], bh[fn], bl[fn])
                }
        }
    }

    // epilogue; C layout: col = lane&15, row = (lane>>4)*4 + reg  [m89-verified]
#pragma unroll
    for (int fm = 0; fm < 4; fm++)
#pragma unroll
        for (int fn = 0; fn < 2; fn++) {
            const int gm0 = tile_m + wm + fm * 16 + lr * 4;
            const int gn  = tile_n + wn + fn * 16 + lc;
            const float bv = bias[gn];
            if (mode == 2) {
                int bb = gm0 >> 11, ss = gm0 & (S - 1);
                int hh = gn >> 6,  dd = gn & 63;
                float4 o = {acc[fm][fn][0] + bv, acc[fm][fn][1] + bv,
                            acc[fm][fn][2] + bv, acc[fm][fn][3] + bv};
                *(float4*)&Cout[((size_t)(bb * H + hh) * 64 + dd) * S + ss] = o;
            } else {
#pragma unroll
                for (int r = 0; r < 4; r++) {
                    int gm = gm0 + r;
                    float val = acc[fm][fn][r] + bv;
                    if (mode == 0) {
                        Cout[(size_t)gm * D + gn] = val;
                    } else {
                        int bb = gm >> 11, ss = gm & (S - 1);
                        int hh = gn >> 6,  dd = gn & 63;
                        Cout[(((size_t)(bb * H + hh) * S + ss) << 6) + dd] = val;
                    }
                }
            }
        }
}

// ---------------------------------------------------------------------------
// scores: Sc = 0.125 * Q K^T with mask semantics; raw masked scores written;
// per-(row, 128-col tile) softmax partials to aux.  Tile 128x128, K=64 staged
// in two 32-halves.  4 waves (2x2), wave = 64x64 (4x4 frags).
// ---------------------------------------------------------------------------
#define PADK32 40   // 32 + 8 shorts: 80B rows

__global__ __launch_bounds__(256) void scores_mm(
    const float* __restrict__ Q, const float* __restrict__ Kp,
    const float* __restrict__ mask, float* __restrict__ Sc,
    float2* __restrict__ aux)
{
    __shared__ __align__(16) short Qh[128][PADK32], Ql[128][PADK32];
    __shared__ __align__(16) short Kh[128][PADK32], Kl[128][PADK32];
    __shared__ float smx[2][128], sls[2][128];

    const int tid  = threadIdx.x;
    const int lane = tid & 63, wid = tid >> 6;
    const int wm = (wid >> 1) * 64, wn = (wid & 1) * 64;
    const int lr = lane >> 4, lc = lane & 15;
    const int bh = blockIdx.z, b = bh >> 4;
    const int tile_m = blockIdx.y * 128, tile_n = blockIdx.x * 128;

    const float* Qg = Q  + (((size_t)bh * S) << 6);
    const float* Kg = Kp + (((size_t)bh * S) << 6);

    f32x4 acc[4][4] = {};

    for (int k0 = 0; k0 < 64; k0 += 32) {
        __syncthreads();
        // 128x32 fp32 = 256 16-float segs each; 1 Q-seg + 1 K-seg per thread
        const int row = tid >> 1, kseg = (tid & 1) * 16;
        {
            float x[16];
            load16((const float4*)&Qg[((size_t)(tile_m + row) << 6) + k0 + kseg], x);
            split16_store(x, &Qh[row][kseg], &Ql[row][kseg]);
        }
        {
            float x[16];
            load16((const float4*)&Kg[((size_t)(tile_n + row) << 6) + k0 + kseg], x);
            split16_store(x, &Kh[row][kseg], &Kl[row][kseg]);
        }
        __syncthreads();
        const int ko = lr * 8;
        bfrag qh[4], ql[4], kh[4], kl[4];
#pragma unroll
        for (int fm = 0; fm < 4; fm++) {
            qh[fm] = *(const bfrag*)&Qh[wm + fm * 16 + lc][ko];
            ql[fm] = *(const bfrag*)&Ql[wm + fm * 16 + lc][ko];
        }
#pragma unroll
        for (int fn = 0; fn < 4; fn++) {
            kh[fn] = *(const bfrag*)&Kh[wn + fn * 16 + lc][ko];
            kl[fn] = *(const bfrag*)&Kl[wn + fn * 16 + lc][ko];
        }
#pragma unroll
        for (int fm = 0; fm < 4; fm++)
#pragma unroll
            for (int fn = 0; fn < 4; fn++) {
                MFMA3(acc[fm][fn], qh[fm], ql[fm], kh[fn], kl[fn])
            }
    }

    const float* mb = mask + (size_t)b * S * S;
    float* Sh = Sc + (size_t)bh * S * S;
#pragma unroll
    for (int fm = 0; fm < 4; fm++)
#pragma unroll
        for (int r = 0; r < 4; r++) {
            const int lrow = wm + fm * 16 + lr * 4 + r;
            const int gm = tile_m + lrow;
            float sc[4];
#pragma unroll
            for (int fn = 0; fn < 4; fn++) {
                const int gn = tile_n + wn + fn * 16 + lc;
                float v = acc[fm][fn][r] * 0.125f;
                v *= mb[(size_t)gm * S + gn];
                if (v == 0.0f) v = NEG_BIG_F;
                sc[fn] = v;
                Sh[(size_t)gm * S + gn] = v;
            }
            float mx = fmaxf(fmaxf(sc[0], sc[1]), fmaxf(sc[2], sc[3]));
#pragma unroll
            for (int d2 = 1; d2 < 16; d2 <<= 1) mx = fmaxf(mx, __shfl_xor(mx, d2));
            float ls = __expf(sc[0] - mx) + __expf(sc[1] - mx) +
                       __expf(sc[2] - mx) + __expf(sc[3] - mx);
#pragma unroll
            for (int d2 = 1; d2 < 16; d2 <<= 1) ls += __shfl_xor(ls, d2);
            if (lc == 0) { smx[wn >> 6][lrow] = mx; sls[wn >> 6][lrow] = ls; }
        }
    __syncthreads();
    if (tid < 128) {
        float m0 = smx[0][tid], m1 = smx[1][tid];
        float mx = fmaxf(m0, m1);
        float ls = sls[0][tid] * __expf(m0 - mx) + sls[1][tid] * __expf(m1 - mx);
        aux[((size_t)bh * S + tile_m + tid) * NT + blockIdx.x] = make_float2(mx, ls);
    }
}

// ---------------------------------------------------------------------------
__global__ __launch_bounds__(256) void reduce_stats(
    const float2* __restrict__ aux, float2* __restrict__ stats)
{
    const int row = blockIdx.x * 256 + threadIdx.x;   // < B*H*S
    const float2* a = aux + (size_t)row * NT;
    float m = -3.0e38f;
#pragma unroll
    for (int t = 0; t < NT; t++) m = fmaxf(m, a[t].x);
    float l = 0.0f;
#pragma unroll
    for (int t = 0; t < NT; t++) l += a[t].y * __expf(a[t].x - m);
    stats[row] = make_float2(m, 1.0f / l);
}

// ---------------------------------------------------------------------------
// pv: normalize raw scores on the fly (p = exp(s-m)*inv), write alignment
// back in place, Ctx = P @ V via bf16x3 MFMA with V^T [bh][64][S].
// Tile 64x64, BK=64, 4 waves (2x2), wave = 32x32 (2x2 frags).
// ---------------------------------------------------------------------------
__global__ __launch_bounds__(256) void pv_mm(
    float* __restrict__ P, const float* __restrict__ VT,
    const float2* __restrict__ stats, float* __restrict__ Ctx)
{
    __shared__ __align__(16) short Ph[64][PADK], Pl[64][PADK];
    __shared__ __align__(16) short Vh[64][PADK], Vl[64][PADK];
    __shared__ float2 st[64];

    const int tid  = threadIdx.x;
    const int lane = tid & 63, wid = tid >> 6;
    const int wm = (wid >> 1) * 32, wn = (wid & 1) * 32;
    const int lr = lane >> 4, lc = lane & 15;
    const int tile_m = blockIdx.x * 64;
    const int bh = blockIdx.y, b = bh >> 4, h = bh & 15;

    float* Pg = P + (size_t)bh * S * S;
    const float* Vg = VT + (((size_t)bh) << 6) * S;

    if (tid < 64) st[tid] = stats[(size_t)bh * S + tile_m + tid];
    __syncthreads();

    const int prow = tid >> 2, pseg = (tid & 3) * 16;
    const float2 ms = st[prow];

    f32x4 acc[2][2] = {};

    for (int k0 = 0; k0 < S; k0 += 64) {
        // P tile 64x64: load raw, normalize, write back, split into LDS
        {
            float4* gp = (float4*)&Pg[(size_t)(tile_m + prow) * S + k0 + pseg];
            float x[16];
#pragma unroll
            for (int q = 0; q < 4; q++) {
                float4 t = gp[q];
                t.x = __expf(t.x - ms.x) * ms.y;
                t.y = __expf(t.y - ms.x) * ms.y;
                t.z = __expf(t.z - ms.x) * ms.y;
                t.w = __expf(t.w - ms.x) * ms.y;
                gp[q] = t;
                x[q*4+0] = t.x; x[q*4+1] = t.y; x[q*4+2] = t.z; x[q*4+3] = t.w;
            }
            split16_store(x, &Ph[prow][pseg], &Pl[prow][pseg]);
        }
        // V^T tile 64(d) x 64(k)
        {
            float x[16];
            load16((const float4*)&Vg[(size_t)prow * S + k0 + pseg], x);
            split16_store(x, &Vh[prow][pseg], &Vl[prow][pseg]);
        }
        __syncthreads();
#pragma unroll
        for (int ks = 0; ks < 2; ks++) {
            const int ko = ks * 32 + lr * 8;
            bfrag ah[2], al[2], bh2[2], bl2[2];
#pragma unroll
            for (int fm = 0; fm < 2; fm++) {
                ah[fm] = *(const bfrag*)&Ph[wm + fm * 16 + lc][ko];
                al[fm] = *(const bfrag*)&Pl[wm + fm * 16 + lc][ko];
            }
#pragma unroll
            for (int fn = 0; fn < 2; fn++) {
                bh2[fn] = *(const bfrag*)&Vh[wn + fn * 16 + lc][ko];
                bl2[fn] = *(const bfrag*)&Vl[wn + fn * 16 + lc][ko];
            }
#pragma unroll
            for (int fm = 0; fm < 2; fm++)
#pragma unroll
                for (int fn = 0; fn < 2; fn++) {
                    MFMA3(acc[fm][fn], ah[fm], al[fm], bh2[fn], bl2[fn])
                }
        }
        __syncthreads();
    }

#pragma unroll
    for (int fm = 0; fm < 2; fm++)
#pragma unroll
        for (int fn = 0; fn < 2; fn++)
#pragma unroll
            for (int r = 0; r < 4; r++) {
                int s_ = tile_m + wm + fm * 16 + lr * 4 + r;
                int dcol = h * 64 + wn + fn * 16 + lc;
                Ctx[((size_t)b * S + s_) * D + dcol] = acc[fm][fn][r];
            }
}

// ---------------------------------------------------------------------------
extern "C" void kernel_launch(void* const* d_in, const int* in_sizes, int n_in,
                              void* d_out, int out_size, void* d_ws, size_t ws_size,
                              hipStream_t stream)
{
    const float* q    = (const float*)d_in[0];
    const float* v    = (const float*)d_in[1];
    const float* mask = (const float*)d_in[2];
    const float* wq_w = (const float*)d_in[3];
    const float* wq_b = (const float*)d_in[4];
    const float* wk_w = (const float*)d_in[5];
    const float* wk_b = (const float*)d_in[6];
    const float* wv_w = (const float*)d_in[7];
    const float* wv_b = (const float*)d_in[8];
    const float* wo_w = (const float*)d_in[9];
    const float* wo_b = (const float*)d_in[10];

    float* out_heads = (float*)d_out;                       // [B,S,D]
    float* out_align = (float*)d_out + (size_t)B * S * D;   // [B,H,S,S]

    // ws layout (floats), 16M floats = 64 MB total, lifetime-safe overlays:
    //  [0,1M)  wqT   [1M,2M) wkT   [2M,3M) wvT   [3M,4M) woT
    //  aux (2M floats) overlays wqT+wkT  (dead after QKV projections)
    //  stats (128K floats) overlays wvT start (dead after V projection)
    //  [4M,8M)  Qw  -> later reused as Ctx (Qw dead after scores)
    //  [8M,12M) Kw
    //  [12M,16M) VT
    float* wsf = (float*)d_ws;
    const size_t M1 = 1u << 20;
    float*  WT0 = wsf;
    float*  WT1 = wsf + M1;
    float*  WT2 = wsf + 2 * M1;
    float*  WT3 = wsf + 3 * M1;
    float*  Qw  = wsf + 4 * M1;
    float*  Kw  = wsf + 8 * M1;
    float*  VT  = wsf + 12 * M1;
    float*  Ctx = Qw;
    float2* aux   = (float2*)wsf;
    float2* stats = (float2*)(wsf + 2 * M1);

    dim3 tg(16, 16);
    transpose_w<<<tg, 256, 0, stream>>>(wq_w, WT0);
    transpose_w<<<tg, 256, 0, stream>>>(wk_w, WT1);
    transpose_w<<<tg, 256, 0, stream>>>(wv_w, WT2);
    transpose_w<<<tg, 256, 0, stream>>>(wo_w, WT3);

    dim3 pg(D / 64, M_ROWS / 128);        // (16, 32)
    mm_proj<<<pg, 256, 0, stream>>>(q, WT0, wq_b, Qw, 1);
    mm_proj<<<pg, 256, 0, stream>>>(v, WT1, wk_b, Kw, 1);
    mm_proj<<<pg, 256, 0, stream>>>(v, WT2, wv_b, VT, 2);

    dim3 sg(S / 128, S / 128, B * H);     // (16, 16, 32)
    scores_mm<<<sg, 256, 0, stream>>>(Qw, Kw, mask, out_align, aux);

    reduce_stats<<<dim3((B * H * S) / 256), 256, 0, stream>>>(aux, stats);

    dim3 vg(S / 64, B * H);               // (32, 32)
    pv_mm<<<vg, 256, 0, stream>>>(out_align, VT, stats, Ctx);

    mm_proj<<<pg, 256, 0, stream>>>(Ctx, WT3, wo_b, out_heads, 0);
}